// Round 5
// baseline (20.328 us; speedup 1.0000x reference)
//
#include <hip/hip_runtime.h>
#include <math.h>

// 20-layer iterative resource allocation, [K=4096, U=512] fp32.
// One wave per row, 8 elems/lane (4x float2 -> v_pk_* packed fp32).
// Layer math collapsed; 1/(S-aPH) expanded to first order so BOTH row
// sums become polynomial in aPH and fuse into ONE reduction pass:
//   S1 = sum(aPH), S2 = sum(P*aPH), S3 = sum(P*aPH^2)
//   S  = n0 + S1, rS = 1/S
//   c  = rS^2*(S2 + rS*S3)
//   a' = clip(a + ph*(lr*rS + aph*(lr*rS^2)) - (lr*c)*h, 0, 1)
// Reduction is all-VALU: DPP row_shr 1/2/4/8 + row_bcast15/31 -> lane 63
// -> readlane to SGPR. Zero LDS ops, zero lgkmcnt stalls, no barriers.

typedef float v2f __attribute__((ext_vector_type(2)));

constexpr int K = 4096;
constexpr int U = 512;
constexpr int NLAYERS = 20;

template <int CTRL, int RMASK>
__device__ __forceinline__ float dpp_add(float v) {
    int t = __builtin_amdgcn_update_dpp(0, __float_as_int(v), CTRL, RMASK, 0xF, true);
    return v + __int_as_float(t);
}

// Full-wave sum -> SGPR (uniform). Canonical GCN DPP reduce, result lane 63.
__device__ __forceinline__ float wave_sum_uniform(float v) {
    v = dpp_add<0x111, 0xF>(v);   // row_shr:1
    v = dpp_add<0x112, 0xF>(v);   // row_shr:2
    v = dpp_add<0x114, 0xF>(v);   // row_shr:4
    v = dpp_add<0x118, 0xF>(v);   // row_shr:8  -> lane 15/31/47/63 = row sums
    v = dpp_add<0x142, 0xA>(v);   // row_bcast:15 -> rows 1,3
    v = dpp_add<0x143, 0xC>(v);   // row_bcast:31 -> rows 2,3; lane 63 = total
    return __int_as_float(__builtin_amdgcn_readlane(__float_as_int(v), 63));
}

__global__ __launch_bounds__(256, 4) void ra_kernel(
    const float* __restrict__ H,
    const float* __restrict__ P,
    const float* __restrict__ n0p,
    const float* __restrict__ stepsz,
    const float* __restrict__ a_init,
    float* __restrict__ out)
{
    const int wave = threadIdx.x >> 6;
    const int lane = threadIdx.x & 63;
    const int row  = blockIdx.x * 4 + wave;
    const float n0 = n0p[0];

    const float* __restrict__ Hrow = H      + (size_t)row * U;
    const float* __restrict__ Prow = P      + (size_t)row * U;
    const float* __restrict__ Arow = a_init + (size_t)row * U;

    v2f h[4], ph[4], p2h[4], a[4];

    #pragma unroll
    for (int j = 0; j < 2; ++j) {
        const int u = j * 256 + lane * 4;
        const float4 hv = *reinterpret_cast<const float4*>(Hrow + u);
        const float4 pv = *reinterpret_cast<const float4*>(Prow + u);
        const float4 av = *reinterpret_cast<const float4*>(Arow + u);
        h[j*2+0] = v2f{hv.x, hv.y}; h[j*2+1] = v2f{hv.z, hv.w};
        v2f p0 = v2f{pv.x, pv.y}, p1 = v2f{pv.z, pv.w};
        ph[j*2+0] = p0 * h[j*2+0];  ph[j*2+1] = p1 * h[j*2+1];
        p2h[j*2+0] = p0 * ph[j*2+0]; p2h[j*2+1] = p1 * ph[j*2+1];
        a[j*2+0] = v2f{av.x, av.y}; a[j*2+1] = v2f{av.z, av.w};
    }

    #pragma unroll
    for (int j = 0; j < 4; ++j) {
        // sigmoid (one-time)
        a[j].x = __builtin_amdgcn_rcpf(1.0f + __expf(-a[j].x));
        a[j].y = __builtin_amdgcn_rcpf(1.0f + __expf(-a[j].y));
    }

    #pragma unroll
    for (int l = 0; l < NLAYERS; ++l) {
        const float lr = stepsz[l];

        // fused phase: aPH, P*aPH and the three partial sums
        v2f aph[4];
        v2f acc1a = v2f{0,0}, acc1b = v2f{0,0};
        v2f acc2a = v2f{0,0}, acc2b = v2f{0,0};
        v2f acc3a = v2f{0,0}, acc3b = v2f{0,0};
        #pragma unroll
        for (int j = 0; j < 4; ++j) {
            aph[j] = a[j] * ph[j];                 // pk_mul
            const v2f pa = a[j] * p2h[j];          // P*aPH = a*P^2*H
            if (j & 1) {
                acc1b += aph[j];
                acc2b += pa;
                acc3b = pa * aph[j] + acc3b;       // pk_fma
            } else {
                acc1a += aph[j];
                acc2a += pa;
                acc3a = pa * aph[j] + acc3a;
            }
        }
        const v2f s1v = acc1a + acc1b;
        const v2f s2v = acc2a + acc2b;
        const v2f s3v = acc3a + acc3b;

        // one fused all-VALU reduction (3 independent chains pipeline)
        const float S1 = wave_sum_uniform(s1v.x + s1v.y);
        const float S2 = wave_sum_uniform(s2v.x + s2v.y);
        const float S3 = wave_sum_uniform(s3v.x + s3v.y);

        const float S    = n0 + S1;
        const float rS   = __builtin_amdgcn_rcpf(S);
        const float rS2  = rS * rS;
        const float c    = rS2 * fmaf(rS, S3, S2);   // c = rS^2*(S2 + rS*S3)
        const float sA   = lr * rS;                  // lr/S
        const float sB   = lr * rS2;                 // lr/S^2
        const float nclr = -(lr * c);

        const v2f sAv   = v2f{sA, sA};
        const v2f sBv   = v2f{sB, sB};
        const v2f nclrv = v2f{nclr, nclr};

        // a' = clip(a + ph*(sA + aph*sB) + nclr*h)
        #pragma unroll
        for (int j = 0; j < 4; ++j) {
            const v2f tmp = aph[j] * sBv + sAv;    // pk_fma
            v2f an = ph[j] * tmp + a[j];           // pk_fma
            an = h[j] * nclrv + an;                // pk_fma
            an.x = fminf(fmaxf(an.x, 0.0f), 1.0f); // v_med3
            an.y = fminf(fmaxf(an.y, 0.0f), 1.0f);
            a[j] = an;
        }
    }

    float* __restrict__ Orow = out + (size_t)row * U;
    #pragma unroll
    for (int j = 0; j < 2; ++j) {
        const int u = j * 256 + lane * 4;
        *reinterpret_cast<float4*>(Orow + u) =
            make_float4(a[j*2+0].x, a[j*2+0].y, a[j*2+1].x, a[j*2+1].y);
    }
}

extern "C" void kernel_launch(void* const* d_in, const int* in_sizes, int n_in,
                              void* d_out, int out_size, void* d_ws, size_t ws_size,
                              hipStream_t stream) {
    const float* H  = (const float*)d_in[0];
    const float* P  = (const float*)d_in[1];
    const float* n0 = (const float*)d_in[2];
    const float* ss = (const float*)d_in[3];
    const float* ai = (const float*)d_in[4];
    float* out = (float*)d_out;

    ra_kernel<<<K / 4, 256, 0, stream>>>(H, P, n0, ss, ai, out);
}